// Round 3
// baseline (146.426 us; speedup 1.0000x reference)
//
#include <hip/hip_runtime.h>

#define TLEN 600
#define PLEN 144
#define KW   25
#define PADW 12                 // KW/2; 12 floats = 48 B (16B aligned)
#define SROW (TLEN + 2*PADW)    // 624
#define RPB  4                  // rows per block
#define NTH  320                // 5 waves
#define CPR  (TLEN/8)           // 75 eight-wide chunks per row
#define NCHUNK (RPB*CPR)        // 300 compute lanes

typedef float f32x4 __attribute__((ext_vector_type(4)));

// Block = 4 rows. Rows staged zero-padded in LDS. Each compute lane produces
// 8 consecutive outputs: the 8 overlapping 25-tap windows span exactly
// s[8i .. 8i+31] = 8 aligned ds_read_b128; elements 12..19 of that span ARE
// x[8i..8i+7] (PADW==12). daily[t] = mk[t % 144] (576 = 4*144; the 24-tail
// wraps to phases 0..23). Outputs stored nontemporal (write-once streams).
__global__ __launch_bounds__(NTH) void decomp_kernel(
    const float* __restrict__ x,
    float* __restrict__ hf,
    float* __restrict__ daily,
    float* __restrict__ trend)
{
    __shared__ float s[RPB][SROW];
    __shared__ float mk[RPB][PLEN];

    const int tid = threadIdx.x;
    const size_t row0 = (size_t)blockIdx.x * RPB;
    const float* xb = x + row0 * TLEN;

    // --- stage 4 rows: 600 float4 chunks over 320 lanes ---
    for (int i = tid; i < RPB * (TLEN / 4); i += NTH) {
        int r = i / (TLEN / 4);          // /150 -> magic mul
        int c = i - r * (TLEN / 4);
        float4 v = ((const float4*)(xb + r * TLEN))[c];
        *(float4*)&s[r][PADW + 4 * c] = v;    // byte 48 + 16c: aligned
    }
    // --- zero pads: 4 rows x 24 floats = 96 lanes ---
    if (tid < RPB * 2 * PADW) {
        int r = tid / (2 * PADW);
        int k = tid - r * (2 * PADW);
        int idx = (k < PADW) ? k : (SROW - 2 * PADW + k);  // 0..11 | 612..623
        s[r][idx] = 0.0f;
    }
    __syncthreads();

    // --- per-phase means over 4 full periods: 576 items over 320 lanes ---
    for (int i = tid; i < RPB * PLEN; i += NTH) {
        int r = i / PLEN;
        int p = i - r * PLEN;
        const float* sp = &s[r][PADW + p];
        mk[r][p] = 0.25f * ((sp[0] + sp[144]) + (sp[288] + sp[432]));
    }
    __syncthreads();

    // --- compute + store: 8 outputs per lane, 300 lanes ---
    if (tid < NCHUNK) {
        int r = tid / CPR;               // /75 -> magic mul
        int i = tid - r * CPR;

        const float4* w = (const float4*)&s[r][8 * i];   // 32B aligned
        float4 v0 = w[0], v1 = w[1], v2 = w[2], v3 = w[3];
        float4 v4 = w[4], v5 = w[5], v6 = w[6], v7 = w[7];

        float ws[8];
        ws[0] = (((v0.x + v0.y) + (v0.z + v0.w)) + ((v1.x + v1.y) + (v1.z + v1.w)))
              + (((v2.x + v2.y) + (v2.z + v2.w)) + ((v3.x + v3.y) + (v3.z + v3.w)))
              + (((v4.x + v4.y) + (v4.z + v4.w)) + ((v5.x + v5.y) + (v5.z + v5.w)))
              + v6.x;
        ws[1] = ws[0] - v0.x + v6.y;
        ws[2] = ws[1] - v0.y + v6.z;
        ws[3] = ws[2] - v0.z + v6.w;
        ws[4] = ws[3] - v0.w + v7.x;
        ws[5] = ws[4] - v1.x + v7.y;
        ws[6] = ws[5] - v1.y + v7.z;
        ws[7] = ws[6] - v1.z + v7.w;

        const float inv = 1.0f / (float)KW;
        float tr[8];
#pragma unroll
        for (int j = 0; j < 8; ++j) tr[j] = ws[j] * inv;

        int p = 8 * (i - 18 * (i / 18));           // (8i) % 144, 8-aligned
        float4 d0 = *(const float4*)&mk[r][p];
        float4 d1 = *(const float4*)&mk[r][p + 4];
        float dd[8] = {d0.x, d0.y, d0.z, d0.w, d1.x, d1.y, d1.z, d1.w};

        float xv[8] = {v3.x, v3.y, v3.z, v3.w, v4.x, v4.y, v4.z, v4.w};

        float h[8];
#pragma unroll
        for (int j = 0; j < 8; ++j)
            h[j] = __builtin_fmaf(tr[j] + dd[j], -0.5f, xv[j]);

        size_t ob = (row0 + r) * TLEN + 8 * i;     // 32B aligned
        __builtin_nontemporal_store(*(f32x4*)&h[0],  (f32x4*)(hf + ob));
        __builtin_nontemporal_store(*(f32x4*)&h[4],  (f32x4*)(hf + ob + 4));
        __builtin_nontemporal_store(*(f32x4*)&dd[0], (f32x4*)(daily + ob));
        __builtin_nontemporal_store(*(f32x4*)&dd[4], (f32x4*)(daily + ob + 4));
        __builtin_nontemporal_store(*(f32x4*)&tr[0], (f32x4*)(trend + ob));
        __builtin_nontemporal_store(*(f32x4*)&tr[4], (f32x4*)(trend + ob + 4));
    }
}

extern "C" void kernel_launch(void* const* d_in, const int* in_sizes, int n_in,
                              void* d_out, int out_size, void* d_ws, size_t ws_size,
                              hipStream_t stream) {
    const float* x = (const float*)d_in[0];
    int total = in_sizes[0];           // 8*32*207*600 = 31,795,200
    int nrows = total / TLEN;          // 52,992 (divisible by 4)

    float* out   = (float*)d_out;
    float* hf    = out;
    float* daily = out + (size_t)total;
    float* trend = out + 2 * (size_t)total;

    decomp_kernel<<<nrows / RPB, NTH, 0, stream>>>(x, hf, daily, trend);
}

// Round 4
// 137.277 us; speedup vs baseline: 1.0666x; 1.0666x over previous
//
#include <hip/hip_runtime.h>

#define TLEN 600
#define PLEN 144
#define KW   25
#define RPB  4            // rows per block
#define NTH  320          // 5 waves
#define CPR  150          // 4-wide chunks per row

// No LDS staging of the row: each lane loads its 28-float window directly
// from global (7 x 16B-aligned dwordx4; neighbors overlap -> L1/L2 hits).
// Only the per-phase means mk[] are cooperative (coalesced global reads,
// 1.2 KB LDS, one barrier). daily[t] = mk[t % 144] (576 = 4*144; the 24-tail
// wraps to phases 0..23). trend divides by 25 always (count_include_pad).
__global__ __launch_bounds__(NTH) void decomp_kernel(
    const float* __restrict__ x,
    float* __restrict__ hf,
    float* __restrict__ daily,
    float* __restrict__ trend)
{
    __shared__ float mk[RPB][PLEN];

    const int tid = threadIdx.x;
    const size_t row0 = (size_t)blockIdx.x * RPB;
    const float* xb = x + row0 * TLEN;

    // --- phase means: 4 rows x 144 phases = 576 items over 320 lanes ---
    // lane with phase p reads x[row*600 + k*144 + p]: consecutive lanes ->
    // consecutive addresses, fully coalesced; also warms L1/L2 for phase B.
    for (int m = tid; m < RPB * PLEN; m += NTH) {
        int r = m / PLEN;
        int p = m - r * PLEN;
        const float* xr = xb + r * TLEN;
        mk[r][p] = 0.25f * ((xr[p] + xr[p + 144]) + (xr[p + 288] + xr[p + 432]));
    }
    __syncthreads();

    // --- compute: 4 rows x 150 four-wide chunks = 600 items over 320 lanes ---
    for (int c = tid; c < RPB * CPR; c += NTH) {
        int r = c / CPR;
        int i = c - r * CPR;
        const float* xr = xb + r * TLEN;
        int base = 4 * i - 12;              // window start (float index)

        float W[28];                        // compile-time indexed -> registers
        if (base >= 0 && base <= TLEN - 28) {
            // interior: 7 aligned float4 loads (byte offset 16i-48, 16B aligned)
#pragma unroll
            for (int j = 0; j < 7; ++j)
                *(float4*)&W[4 * j] = *(const float4*)(xr + base + 4 * j);
        } else {
            // row edge (i<3 or i>146): predicated scalar loads, zero-pad OOB
#pragma unroll
            for (int j = 0; j < 28; ++j) {
                int idx = base + j;
                W[j] = (idx >= 0 && idx < TLEN) ? xr[idx] : 0.0f;
            }
        }

        // 25-tap window sums for the 4 outputs (balanced tree + incremental)
        float s0 = (((W[0]  + W[1])  + (W[2]  + W[3]))  +
                    ((W[4]  + W[5])  + (W[6]  + W[7]))) +
                   (((W[8]  + W[9])  + (W[10] + W[11])) +
                    ((W[12] + W[13]) + (W[14] + W[15]))) +
                   (((W[16] + W[17]) + (W[18] + W[19])) +
                    ((W[20] + W[21]) + (W[22] + W[23]))) + W[24];
        float s1 = s0 - W[0] + W[25];
        float s2 = s1 - W[1] + W[26];
        float s3 = s2 - W[2] + W[27];

        const float inv = 1.0f / (float)KW;
        float4 tr = make_float4(s0 * inv, s1 * inv, s2 * inv, s3 * inv);

        int p4 = 4 * (i - 36 * (i / 36));   // (4i) % 144, 4-aligned
        float4 d = *(const float4*)&mk[r][p4];

        float4 h;                           // x[4i..4i+3] == W[12..15]
        h.x = __builtin_fmaf(tr.x + d.x, -0.5f, W[12]);
        h.y = __builtin_fmaf(tr.y + d.y, -0.5f, W[13]);
        h.z = __builtin_fmaf(tr.z + d.z, -0.5f, W[14]);
        h.w = __builtin_fmaf(tr.w + d.w, -0.5f, W[15]);

        size_t ob = (row0 + r) * TLEN + 4 * i;
        *(float4*)(hf + ob)    = h;
        *(float4*)(daily + ob) = d;
        *(float4*)(trend + ob) = tr;
    }
}

extern "C" void kernel_launch(void* const* d_in, const int* in_sizes, int n_in,
                              void* d_out, int out_size, void* d_ws, size_t ws_size,
                              hipStream_t stream) {
    const float* x = (const float*)d_in[0];
    int total = in_sizes[0];           // 8*32*207*600 = 31,795,200
    int nrows = total / TLEN;          // 52,992 (divisible by 4)

    float* out   = (float*)d_out;
    float* hf    = out;
    float* daily = out + (size_t)total;
    float* trend = out + 2 * (size_t)total;

    decomp_kernel<<<nrows / RPB, NTH, 0, stream>>>(x, hf, daily, trend);
}

// Round 5
// 95.144 us; speedup vs baseline: 1.5390x; 1.4428x over previous
//
#include <hip/hip_runtime.h>

#define TLEN 600
#define PLEN 144
#define KW   25
#define PADW 12                // KW/2; 12 floats = 48 B (16B aligned)
#define SROW (TLEN + 2*PADW)   // 624
#define RPB  2                 // rows per block
#define NTH  320               // 5 waves
#define NC   (TLEN/4)          // 150 float4 chunks per row

// R2 structure with ONE barrier: phase means are computed from global
// (coalesced; same cache lines the staging loads just touched -> L1/L2 hits)
// concurrently with LDS staging, instead of from LDS after a first barrier.
// Each compute lane produces 4 consecutive outputs; the 4 overlapping 25-tap
// windows span s[4i..4i+27] = 7 aligned ds_read_b128; v3 of that span IS
// x[4i..4i+3] (PADW==12). daily[t] = mk[t % 144] (576 = 4*144; tail wraps).
__global__ __launch_bounds__(NTH) void decomp_kernel(
    const float* __restrict__ x,
    float* __restrict__ hf,
    float* __restrict__ daily,
    float* __restrict__ trend)
{
    __shared__ float s[RPB][SROW];
    __shared__ float mk[RPB][PLEN];

    const int tid = threadIdx.x;
    const size_t row0 = (size_t)blockIdx.x * RPB;
    const float* xb = x + row0 * TLEN;

    // --- stage 2 rows into LDS (300 lanes, one float4 each) ---
    if (tid < RPB * NC) {
        int r = tid >= NC;               // RPB == 2
        int i = tid - r * NC;
        float4 v = ((const float4*)(xb + r * TLEN))[i];
        *(float4*)&s[r][PADW + 4 * i] = v;   // byte 48 + 16i: aligned
    }
    // --- zero pads (48 lanes) ---
    if (tid < RPB * 2 * PADW) {
        int r = tid / (2 * PADW);
        int k = tid - r * (2 * PADW);
        int idx = (k < PADW) ? k : (TLEN + k);   // 0..11 | 612..623
        s[r][idx] = 0.0f;
    }
    // --- phase means from GLOBAL (288 lanes; coalesced, L1/L2 hits) ---
    if (tid < RPB * PLEN) {
        int r = tid >= PLEN;
        int p = tid - r * PLEN;
        const float* xr = xb + r * TLEN;
        mk[r][p] = 0.25f * ((xr[p] + xr[p + 144]) + (xr[p + 288] + xr[p + 432]));
    }
    __syncthreads();

    // --- compute + store: 4 outputs per lane (300 lanes) ---
    if (tid < RPB * NC) {
        int r = tid >= NC;
        int i = tid - r * NC;

        const float4* w = (const float4*)&s[r][4 * i];  // 16B aligned
        float4 v0 = w[0], v1 = w[1], v2 = w[2], v3 = w[3];
        float4 v4 = w[4], v5 = w[5], v6 = w[6];

        float s0 = (((v0.x + v0.y) + (v0.z + v0.w)) + ((v1.x + v1.y) + (v1.z + v1.w)))
                 + (((v2.x + v2.y) + (v2.z + v2.w)) + ((v3.x + v3.y) + (v3.z + v3.w)))
                 + (((v4.x + v4.y) + (v4.z + v4.w)) + ((v5.x + v5.y) + (v5.z + v5.w)))
                 + v6.x;
        float s1 = s0 - v0.x + v6.y;
        float s2 = s1 - v0.y + v6.z;
        float s3 = s2 - v0.z + v6.w;

        const float inv = 1.0f / (float)KW;
        float4 tr = make_float4(s0 * inv, s1 * inv, s2 * inv, s3 * inv);

        int p4 = 4 * (i - 36 * (i / 36));    // (4i) % 144, 4-aligned
        float4 d = *(const float4*)&mk[r][p4];

        float4 h;                            // v3 == x[4i..4i+3]
        h.x = __builtin_fmaf(tr.x + d.x, -0.5f, v3.x);
        h.y = __builtin_fmaf(tr.y + d.y, -0.5f, v3.y);
        h.z = __builtin_fmaf(tr.z + d.z, -0.5f, v3.z);
        h.w = __builtin_fmaf(tr.w + d.w, -0.5f, v3.w);

        size_t ob = (row0 + r) * TLEN + 4 * i;
        *(float4*)(hf + ob)    = h;
        *(float4*)(daily + ob) = d;
        *(float4*)(trend + ob) = tr;
    }
}

extern "C" void kernel_launch(void* const* d_in, const int* in_sizes, int n_in,
                              void* d_out, int out_size, void* d_ws, size_t ws_size,
                              hipStream_t stream) {
    const float* x = (const float*)d_in[0];
    int total = in_sizes[0];           // 8*32*207*600 = 31,795,200
    int nrows = total / TLEN;          // 52,992 (even)

    float* out   = (float*)d_out;
    float* hf    = out;
    float* daily = out + (size_t)total;
    float* trend = out + 2 * (size_t)total;

    decomp_kernel<<<nrows / RPB, NTH, 0, stream>>>(x, hf, daily, trend);
}

// Round 6
// 92.394 us; speedup vs baseline: 1.5848x; 1.0298x over previous
//
#include <hip/hip_runtime.h>

#define TLEN 600
#define PLEN 144
#define KW   25
#define PADW 12                 // KW/2; 12 floats = 3 float4
#define SROW (TLEN + 2*PADW)    // 624 floats per padded row
#define RPB  2                  // rows per block
#define NTH  320                // 5 waves
#define NC   (TLEN/4)           // 150 data chunks per row
#define CROW (SROW/4)           // 156 chunks per padded row (incl. pads)
#define CTOT (RPB*CROW)         // 312 staged chunks per block

// R2 structure, but staging uses global_load_lds (direct HBM->LDS DMA,
// width=16): LDS is a pad-inclusive linear array of 312 float4 chunks, so
// wave w's destination is exactly base + 1024*w + 16*lane (the HW's required
// wave-uniform-base + lane*size layout). Pad chunks are exec-masked out of
// the DMA and zeroed with ds_write by their own lanes. Everything else
// (mk from LDS, 4-wide incremental windows, float4 stores) is R2 verbatim.
__global__ __launch_bounds__(NTH) void decomp_kernel(
    const float* __restrict__ x,
    float* __restrict__ hf,
    float* __restrict__ daily,
    float* __restrict__ trend)
{
    __shared__ float s2[RPB * SROW];   // [r*624 + 0..11 pad | 12..611 data | 612..623 pad]
    __shared__ float mk[RPB][PLEN];

    const int tid = threadIdx.x;
    const size_t row0 = (size_t)blockIdx.x * RPB;
    const float* xb = x + row0 * TLEN;

    // --- stage: one chunk per lane, direct-to-LDS ---
    if (tid < CTOT) {
        int r  = tid >= CROW;               // RPB == 2
        int rc = tid - CROW * r;            // chunk within padded row, 0..155
        // wave-uniform LDS base: this wave's 64-chunk segment
        char* lbase = (char*)s2 + ((tid >> 6) << 10);
        if (rc >= 3 && rc <= 152) {
            // data chunk: x[r*600 + 4*(rc-3) .. +3] -> LDS byte 16*tid
            const float* gp = xb + r * TLEN + 4 * (rc - 3);
            __builtin_amdgcn_global_load_lds(
                (const __attribute__((address_space(1))) void*)gp,
                (__attribute__((address_space(3))) void*)lbase,
                16, 0, 0);
        } else {
            // pad chunk: zero it with a plain LDS store
            *(float4*)((char*)s2 + 16 * tid) = make_float4(0.f, 0.f, 0.f, 0.f);
        }
    }
    __syncthreads();   // drains vmcnt(0): DMA chunks + pad writes complete

    // --- per-phase means from LDS (288 lanes; stride-1 across lanes) ---
    if (tid < RPB * PLEN) {
        int r = tid >= PLEN;
        int p = tid - PLEN * r;
        const float* sp = &s2[SROW * r + PADW + p];
        mk[r][p] = 0.25f * ((sp[0] + sp[144]) + (sp[288] + sp[432]));
    }
    __syncthreads();

    // --- compute + store: 4 outputs per lane (300 lanes) ---
    if (tid < RPB * NC) {
        int r = tid >= NC;
        int i = tid - NC * r;

        // window floats (padded idx) 4i .. 4i+27 = 7 aligned ds_read_b128
        const float4* w = (const float4*)&s2[SROW * r + 4 * i];
        float4 v0 = w[0], v1 = w[1], v2 = w[2], v3 = w[3];
        float4 v4 = w[4], v5 = w[5], v6 = w[6];

        float s0 = (((v0.x + v0.y) + (v0.z + v0.w)) + ((v1.x + v1.y) + (v1.z + v1.w)))
                 + (((v2.x + v2.y) + (v2.z + v2.w)) + ((v3.x + v3.y) + (v3.z + v3.w)))
                 + (((v4.x + v4.y) + (v4.z + v4.w)) + ((v5.x + v5.y) + (v5.z + v5.w)))
                 + v6.x;
        float s1 = s0 - v0.x + v6.y;
        float s2v = s1 - v0.y + v6.z;
        float s3 = s2v - v0.z + v6.w;

        const float inv = 1.0f / (float)KW;
        float4 tr = make_float4(s0 * inv, s1 * inv, s2v * inv, s3 * inv);

        int p4 = 4 * (i - 36 * (i / 36));    // (4i) % 144, 4-aligned
        float4 d = *(const float4*)&mk[r][p4];

        float4 h;                            // v3 == x[4i..4i+3]
        h.x = __builtin_fmaf(tr.x + d.x, -0.5f, v3.x);
        h.y = __builtin_fmaf(tr.y + d.y, -0.5f, v3.y);
        h.z = __builtin_fmaf(tr.z + d.z, -0.5f, v3.z);
        h.w = __builtin_fmaf(tr.w + d.w, -0.5f, v3.w);

        size_t ob = (row0 + r) * TLEN + 4 * i;
        *(float4*)(hf + ob)    = h;
        *(float4*)(daily + ob) = d;
        *(float4*)(trend + ob) = tr;
    }
}

extern "C" void kernel_launch(void* const* d_in, const int* in_sizes, int n_in,
                              void* d_out, int out_size, void* d_ws, size_t ws_size,
                              hipStream_t stream) {
    const float* x = (const float*)d_in[0];
    int total = in_sizes[0];           // 8*32*207*600 = 31,795,200
    int nrows = total / TLEN;          // 52,992 (even)

    float* out   = (float*)d_out;
    float* hf    = out;
    float* daily = out + (size_t)total;
    float* trend = out + 2 * (size_t)total;

    decomp_kernel<<<nrows / RPB, NTH, 0, stream>>>(x, hf, daily, trend);
}

// Round 7
// 79.990 us; speedup vs baseline: 1.8305x; 1.1551x over previous
//
#include <hip/hip_runtime.h>

#define TLEN 600
#define PLEN 144
#define KW   25
#define PADW 12                 // KW/2; 12 floats = 3 float4
#define SROW (TLEN + 2*PADW)    // 624 floats per padded row
#define RPB  2                  // rows per block
#define NTH  320                // 5 waves
#define NC   (TLEN/4)           // 150 data chunks per row
#define CROW (SROW/4)           // 156 chunks per padded row (incl. pads)
#define CTOT (RPB*CROW)         // 312 staged chunks per block

typedef float f32x4 __attribute__((ext_vector_type(4)));

// R6 (global_load_lds staging, two barriers, 4-wide windows) verbatim,
// with ONE isolated change: the three output streams use nontemporal
// stores (nt flag) so the 382 MB/replay write traffic does not allocate
// in the 256 MiB L3 and evict the 127 MB input between graph replays.
__global__ __launch_bounds__(NTH) void decomp_kernel(
    const float* __restrict__ x,
    float* __restrict__ hf,
    float* __restrict__ daily,
    float* __restrict__ trend)
{
    __shared__ float s2[RPB * SROW];   // [r*624: 0..11 pad | 12..611 data | 612..623 pad]
    __shared__ float mk[RPB][PLEN];

    const int tid = threadIdx.x;
    const size_t row0 = (size_t)blockIdx.x * RPB;
    const float* xb = x + row0 * TLEN;

    // --- stage: one chunk per lane, direct HBM->LDS DMA ---
    if (tid < CTOT) {
        int r  = tid >= CROW;               // RPB == 2
        int rc = tid - CROW * r;            // chunk within padded row, 0..155
        char* lbase = (char*)s2 + ((tid >> 6) << 10);  // wave-uniform base
        if (rc >= 3 && rc <= 152) {
            const float* gp = xb + r * TLEN + 4 * (rc - 3);
            __builtin_amdgcn_global_load_lds(
                (const __attribute__((address_space(1))) void*)gp,
                (__attribute__((address_space(3))) void*)lbase,
                16, 0, 0);
        } else {
            *(float4*)((char*)s2 + 16 * tid) = make_float4(0.f, 0.f, 0.f, 0.f);
        }
    }
    __syncthreads();   // drains vmcnt(0): DMA + pad writes complete

    // --- per-phase means from LDS (288 lanes) ---
    if (tid < RPB * PLEN) {
        int r = tid >= PLEN;
        int p = tid - PLEN * r;
        const float* sp = &s2[SROW * r + PADW + p];
        mk[r][p] = 0.25f * ((sp[0] + sp[144]) + (sp[288] + sp[432]));
    }
    __syncthreads();

    // --- compute + store: 4 outputs per lane (300 lanes) ---
    if (tid < RPB * NC) {
        int r = tid >= NC;
        int i = tid - NC * r;

        const float4* w = (const float4*)&s2[SROW * r + 4 * i];  // aligned
        float4 v0 = w[0], v1 = w[1], v2 = w[2], v3 = w[3];
        float4 v4 = w[4], v5 = w[5], v6 = w[6];

        float s0 = (((v0.x + v0.y) + (v0.z + v0.w)) + ((v1.x + v1.y) + (v1.z + v1.w)))
                 + (((v2.x + v2.y) + (v2.z + v2.w)) + ((v3.x + v3.y) + (v3.z + v3.w)))
                 + (((v4.x + v4.y) + (v4.z + v4.w)) + ((v5.x + v5.y) + (v5.z + v5.w)))
                 + v6.x;
        float s1  = s0  - v0.x + v6.y;
        float s2v = s1  - v0.y + v6.z;
        float s3  = s2v - v0.z + v6.w;

        const float inv = 1.0f / (float)KW;
        f32x4 tr = {s0 * inv, s1 * inv, s2v * inv, s3 * inv};

        int p4 = 4 * (i - 36 * (i / 36));    // (4i) % 144, 4-aligned
        float4 dd = *(const float4*)&mk[r][p4];
        f32x4 d = {dd.x, dd.y, dd.z, dd.w};

        f32x4 h;                             // v3 == x[4i..4i+3]
        h.x = __builtin_fmaf(tr.x + d.x, -0.5f, v3.x);
        h.y = __builtin_fmaf(tr.y + d.y, -0.5f, v3.y);
        h.z = __builtin_fmaf(tr.z + d.z, -0.5f, v3.z);
        h.w = __builtin_fmaf(tr.w + d.w, -0.5f, v3.w);

        size_t ob = (row0 + r) * TLEN + 4 * i;
        __builtin_nontemporal_store(h,  (f32x4*)(hf + ob));
        __builtin_nontemporal_store(d,  (f32x4*)(daily + ob));
        __builtin_nontemporal_store(tr, (f32x4*)(trend + ob));
    }
}

extern "C" void kernel_launch(void* const* d_in, const int* in_sizes, int n_in,
                              void* d_out, int out_size, void* d_ws, size_t ws_size,
                              hipStream_t stream) {
    const float* x = (const float*)d_in[0];
    int total = in_sizes[0];           // 8*32*207*600 = 31,795,200
    int nrows = total / TLEN;          // 52,992 (even)

    float* out   = (float*)d_out;
    float* hf    = out;
    float* daily = out + (size_t)total;
    float* trend = out + 2 * (size_t)total;

    decomp_kernel<<<nrows / RPB, NTH, 0, stream>>>(x, hf, daily, trend);
}